// Round 8
// baseline (292.753 us; speedup 1.0000x reference)
//
#include <hip/hip_runtime.h>
#include <hip/hip_bf16.h>

#define NQ       131072     // 32*4096 queries
#define KC       1024       // codes
#define DIM      64
#define MARGIN_P 1.5e-3f    // covers 2*step(4.88e-4) pack quant + bf16-split + e2~3.0 approx
#define RGRID    2048       // rescue grid (blocks)

typedef __attribute__((ext_vector_type(8))) short  s8bf;   // 8 bf16 (4 VGPRs)
typedef __attribute__((ext_vector_type(4))) float  f32x4;  // MFMA acc

union BF8 { s8bf v; unsigned short u[8]; };

__device__ __forceinline__ unsigned short f2bf_u(float f) {
    union { __hip_bfloat16 h; unsigned short u; } cv;
    cv.h = __float2bfloat16(f);
    return cv.u;
}
__device__ __forceinline__ float bfu2f(unsigned short u) {
    union { __hip_bfloat16 h; unsigned short u; } cv;
    cv.u = u;
    return __bfloat162float(cv.h);
}
__device__ __forceinline__ void gl_lds16(const float4* g, float4* l) {
    __builtin_amdgcn_global_load_lds(
        (const __attribute__((address_space(1))) unsigned int*)g,
        (__attribute__((address_space(3))) unsigned int*)l, 16, 0, 0);
}

// ---------- K0: prep codes -> bf16 hi/lo B-frags + f64 rescue consts + zero accs ----------
__global__ __launch_bounds__(256) void k_prep(const float* __restrict__ emb,
                                              unsigned short* __restrict__ wB,
                                              double* __restrict__ wInvD,
                                              double* __restrict__ wB2D,
                                              int* __restrict__ counts,
                                              int* __restrict__ nflag,
                                              float* __restrict__ lossp) {
    const int tid = threadIdx.x;
    if (blockIdx.x == 0) {                     // replaces the 3 hipMemsetAsync calls
        #pragma unroll
        for (int i = 0; i < 4; ++i) counts[tid * 4 + i] = 0;
        if (tid == 0) { *nflag = 0; *lossp = 0.f; }
    }
    int c = blockIdx.x * 256 + tid;            // 4 blocks -> 1024 codes
    if (c >= KC) return;
    float e[DIM];
    const float4* ep = reinterpret_cast<const float4*>(emb + (size_t)c * DIM);
    #pragma unroll
    for (int i = 0; i < 16; ++i) {
        float4 t = ep[i];
        e[4*i+0] = t.x; e[4*i+1] = t.y; e[4*i+2] = t.z; e[4*i+3] = t.w;
    }
    float s = 0.f;
    #pragma unroll
    for (int i = 0; i < DIM; ++i) s += e[i] * e[i];
    float inv = 1.0f / fmaxf(sqrtf(s), 1e-12f);
    const int t = c >> 4, col = c & 15;
    #pragma unroll
    for (int k = 0; k < DIM; ++k) {
        float h = e[k] * inv;
        unsigned short hi = f2bf_u(h);
        unsigned short lo = f2bf_u(h - bfu2f(hi));
        int s_ = k >> 5, g = (k >> 3) & 3, j = k & 7;
        int ln = col + 16 * g;
        wB[((t*4 + s_*2 + 0) * 64 + ln) * 8 + j] = hi;
        wB[((t*4 + s_*2 + 1) * 64 + ln) * 8 + j] = lo;
    }
    double sd = 0.0;
    #pragma unroll
    for (int i = 0; i < DIM; ++i) sd += (double)e[i] * (double)e[i];
    double invd = 1.0 / fmax(sqrt(sd), 1e-12);
    wInvD[c] = invd;
    wB2D[c]  = sd * invd * invd;
}

// ---------- K1: MFMA distances + packed-int argmin (pair-min3) + flag append ----------
// block = 256 thr (4 waves); wave handles 32 queries x all 1024 codes
__global__ __launch_bounds__(256, 4) void k_assign(const float* __restrict__ inp,
                                                   const unsigned short* __restrict__ wB,
                                                   float* __restrict__ idx_out,
                                                   int* __restrict__ flag_list,
                                                   int* __restrict__ nflag) {
    __shared__ s8bf Bt[2048];      // 32 KB: chunk = 8 tiles x 4 frags x 64 lanes
    const int tid  = threadIdx.x;
    const int lane = tid & 63, wv = tid >> 6;
    const int col  = lane & 15, g  = lane >> 4;
    const int qbase = blockIdx.x * 128 + wv * 32;

    BF8 ah[2][2], al[2][2];
    #pragma unroll
    for (int s = 0; s < 2; ++s) {
        const float4* q4 = reinterpret_cast<const float4*>(inp + (size_t)(qbase + 16*s + col) * DIM);
        float4 xa = q4[2*g], xb = q4[2*g + 1], ya = q4[8 + 2*g], yb = q4[9 + 2*g];
        float x[16] = { xa.x, xa.y, xa.z, xa.w, xb.x, xb.y, xb.z, xb.w,
                        ya.x, ya.y, ya.z, ya.w, yb.x, yb.y, yb.z, yb.w };
        float sq = 0.f;
        #pragma unroll
        for (int i = 0; i < 16; ++i) sq += x[i] * x[i];
        sq += __shfl_xor(sq, 16);
        sq += __shfl_xor(sq, 32);
        float inv = 1.0f / fmaxf(sqrtf(sq), 1e-12f);
        #pragma unroll
        for (int i = 0; i < 8; ++i) {
            float h0 = x[i] * inv, h1 = x[8 + i] * inv;
            unsigned short hi0 = f2bf_u(h0);
            unsigned short hi1 = f2bf_u(h1);
            ah[s][0].u[i] = hi0;  al[s][0].u[i] = f2bf_u(h0 - bfu2f(hi0));
            ah[s][1].u[i] = hi1;  al[s][1].u[i] = f2bf_u(h1 - bfu2f(hi1));
        }
    }

    int best[2][4], best2[2][4];
    #pragma unroll
    for (int s = 0; s < 2; ++s)
        #pragma unroll
        for (int r = 0; r < 4; ++r) { best[s][r] = 0x7FFFFFFF; best2[s][r] = 0x7FFFFFFF; }

    for (int ch = 0; ch < 8; ++ch) {           // 8 chunks of 128 codes
        __syncthreads();
        const float4* src = reinterpret_cast<const float4*>(wB) + (size_t)ch * 2048;
        float4* dst = reinterpret_cast<float4*>(Bt);
        #pragma unroll
        for (int i = 0; i < 8; ++i) {
            int idx = i * 256 + tid;
            gl_lds16(&src[idx], &dst[idx]);    // linear: base + lane*16
        }
        __syncthreads();                       // drains vmcnt before use

        for (int nt = 0; nt < 8; nt += 2) {    // tile PAIRS (a = nt, b = nt+1)
            s8bf bh0a = Bt[(nt*4 + 0) * 64 + lane];
            s8bf bl0a = Bt[(nt*4 + 1) * 64 + lane];
            s8bf bh1a = Bt[(nt*4 + 2) * 64 + lane];
            s8bf bl1a = Bt[(nt*4 + 3) * 64 + lane];
            s8bf bh0b = Bt[(nt*4 + 4) * 64 + lane];
            s8bf bl0b = Bt[(nt*4 + 5) * 64 + lane];
            s8bf bh1b = Bt[(nt*4 + 6) * 64 + lane];
            s8bf bl1b = Bt[(nt*4 + 7) * 64 + lane];
            const int code_a = ch * 128 + nt * 16 + col;   // code_b = code_a + 16
            #pragma unroll
            for (int s = 0; s < 2; ++s) {
                f32x4 aa = {0.f, 0.f, 0.f, 0.f};
                f32x4 ab = {0.f, 0.f, 0.f, 0.f};
                aa = __builtin_amdgcn_mfma_f32_16x16x32_bf16(ah[s][0].v, bh0a, aa, 0, 0, 0);
                ab = __builtin_amdgcn_mfma_f32_16x16x32_bf16(ah[s][0].v, bh0b, ab, 0, 0, 0);
                aa = __builtin_amdgcn_mfma_f32_16x16x32_bf16(ah[s][1].v, bh1a, aa, 0, 0, 0);
                ab = __builtin_amdgcn_mfma_f32_16x16x32_bf16(ah[s][1].v, bh1b, ab, 0, 0, 0);
                aa = __builtin_amdgcn_mfma_f32_16x16x32_bf16(ah[s][0].v, bl0a, aa, 0, 0, 0);
                ab = __builtin_amdgcn_mfma_f32_16x16x32_bf16(ah[s][0].v, bl0b, ab, 0, 0, 0);
                aa = __builtin_amdgcn_mfma_f32_16x16x32_bf16(ah[s][1].v, bl1a, aa, 0, 0, 0);
                ab = __builtin_amdgcn_mfma_f32_16x16x32_bf16(ah[s][1].v, bl1b, ab, 0, 0, 0);
                aa = __builtin_amdgcn_mfma_f32_16x16x32_bf16(al[s][0].v, bh0a, aa, 0, 0, 0);
                ab = __builtin_amdgcn_mfma_f32_16x16x32_bf16(al[s][0].v, bh0b, ab, 0, 0, 0);
                aa = __builtin_amdgcn_mfma_f32_16x16x32_bf16(al[s][1].v, bh1a, aa, 0, 0, 0);
                ab = __builtin_amdgcn_mfma_f32_16x16x32_bf16(al[s][1].v, bh1b, ab, 0, 0, 0);
                #pragma unroll
                for (int r = 0; r < 4; ++r) {
                    // e2_k ~= 1 (+-2e-6, absorbed in margin) -> bias const 3.0
                    float dpa = fmaf(-2.0f, aa[r], 3.0f);          // in (0.99, 5.01)
                    float dpb = fmaf(-2.0f, ab[r], 3.0f);
                    int pa = (__float_as_int(dpa) & 0xFFFFFC00) | (code_a & 0x3FF);        // v_bfi
                    int pb = (__float_as_int(dpb) & 0xFFFFFC00) | ((code_a + 16) & 0x3FF); // v_bfi
                    int m  = min(pa, pb);
                    int M  = max(pa, pb);
                    int t2 = max(best[s][r], m);               // uses OLD best
                    best2[s][r] = min(min(best2[s][r], t2), M);  // v_min3
                    best[s][r]  = min(best[s][r], m);
                }
            }
        }
    }

    #pragma unroll
    for (int s = 0; s < 2; ++s) {
        #pragma unroll
        for (int off = 1; off < 16; off <<= 1) {
            #pragma unroll
            for (int r = 0; r < 4; ++r) {
                int ob  = __shfl_xor(best[s][r],  off);
                int ob2 = __shfl_xor(best2[s][r], off);
                int mn  = min(best[s][r], ob);
                int mx  = max(best[s][r], ob);
                best[s][r]  = mn;
                best2[s][r] = min(min(best2[s][r], ob2), mx);
            }
        }
        #pragma unroll
        for (int r = 0; r < 4; ++r) {
            if (col == r) {                    // owner lane for this query row
                int   q  = qbase + 16*s + 4*g + r;
                float d1 = __int_as_float(best[s][r]  & 0xFFFFFC00);
                float d2 = __int_as_float(best2[s][r] & 0xFFFFFC00);
                idx_out[q] = (float)(best[s][r] & 1023);
                if (d2 - d1 < MARGIN_P || d1 >= 4.0f) {  // ambiguous -> f64 rescue
                    int slot = atomicAdd(nflag, 1);
                    flag_list[slot] = q;
                }
            }
        }
    }
}

// ---------- K2: f64 rescore, block-per-flagged-query via global list ----------
__global__ __launch_bounds__(256) void k_rescue(const float* __restrict__ inp,
                                                const float* __restrict__ emb,
                                                const double* __restrict__ wInvD,
                                                const double* __restrict__ wB2D,
                                                const int* __restrict__ flag_list,
                                                const int* __restrict__ nflag,
                                                float* __restrict__ idx_out) {
    __shared__ double xh[DIM];
    __shared__ double Ash;
    __shared__ double sdw[4];
    __shared__ int    siw[4];
    const int tid = threadIdx.x;
    const int lane = tid & 63, wv = tid >> 6;
    const int n = *nflag;

    for (int j = blockIdx.x; j < n; j += gridDim.x) {   // uniform trip per block
        const int q = flag_list[j];
        if (tid < 64) {
            double xv = (double)inp[(size_t)q * DIM + tid];
            double s = xv * xv;
            #pragma unroll
            for (int off = 32; off; off >>= 1) s += __shfl_xor(s, off);
            double dn = fmax(sqrt(s), 1e-12);
            double h  = xv / dn;
            xh[tid] = h;
            double a = h * h;
            #pragma unroll
            for (int off = 32; off; off >>= 1) a += __shfl_xor(a, off);
            if (tid == 0) Ash = a;
        }
        __syncthreads();
        const double A = Ash;

        double bd = 1e300; int bi = 1 << 30;
        for (int c = tid; c < KC; c += 256) {          // 4 codes per thread
            const float* e = emb + (size_t)c * DIM;
            double dot = 0.0;
            #pragma unroll
            for (int i = 0; i < DIM; ++i) dot += xh[i] * (double)e[i];
            double d = (A + wB2D[c]) - 2.0 * (dot * wInvD[c]);
            if (d < bd || (d == bd && c < bi)) { bd = d; bi = c; }
        }
        #pragma unroll
        for (int off = 1; off < 64; off <<= 1) {       // 64-lane (d,i) min-reduce
            double od = __shfl_xor(bd, off);
            int    oi = __shfl_xor(bi, off);
            if (od < bd || (od == bd && oi < bi)) { bd = od; bi = oi; }
        }
        if (lane == 0) { sdw[wv] = bd; siw[wv] = bi; }
        __syncthreads();
        if (tid == 0) {
            double B = sdw[0]; int I = siw[0];
            #pragma unroll
            for (int i = 1; i < 4; ++i)
                if (sdw[i] < B || (sdw[i] == B && siw[i] < I)) { B = sdw[i]; I = siw[i]; }
            idx_out[q] = (float)I;                     // final
        }
        __syncthreads();
    }
}

// ---------- K3: gather (f32 out) + sum((q-f)^2) ----------
__global__ __launch_bounds__(256) void k_gather_loss(const float* __restrict__ inp,
                                                     const float* __restrict__ emb,
                                                     const float* __restrict__ idx_out,
                                                     float* __restrict__ qout,
                                                     float* __restrict__ loss) {
    const int gid = blockIdx.x * 256 + threadIdx.x;    // 524288 threads
    float lsum = 0.f;
    for (int e4 = gid; e4 < NQ * 16; e4 += 524288) {
        int   qi = e4 >> 4;
        int   d4 = e4 & 15;
        int   k  = ((int)idx_out[qi]) & (KC - 1);
        float4 qv = reinterpret_cast<const float4*>(emb + (size_t)k * DIM)[d4];
        float4 fv = reinterpret_cast<const float4*>(inp)[e4];
        float ux = qv.x - fv.x, uy = qv.y - fv.y, uz = qv.z - fv.z, uw = qv.w - fv.w;
        lsum += ux*ux + uy*uy + uz*uz + uw*uw;
        reinterpret_cast<float4*>(qout)[e4] = qv;
    }
    #pragma unroll
    for (int off = 32; off; off >>= 1) lsum += __shfl_xor(lsum, off);
    __shared__ float wsum[4];
    int wid = threadIdx.x >> 6, lane = threadIdx.x & 63;
    if (lane == 0) wsum[wid] = lsum;
    __syncthreads();
    if (threadIdx.x == 0)
        atomicAdd(loss, (wsum[0] + wsum[1]) + (wsum[2] + wsum[3]));
}

// ---------- K4: fused histogram + perplexity/usage/vq_loss (single block) ----------
__global__ __launch_bounds__(1024) void k_stats(const float* __restrict__ idx_out,
                                                float* __restrict__ out3) {
    __shared__ int hist[KC];
    const int t = threadIdx.x;
    hist[t] = 0;
    __syncthreads();
    for (int q = t; q < NQ; q += 1024)
        atomicAdd(&hist[((int)idx_out[q]) & (KC - 1)], 1);
    __syncthreads();
    int c = hist[t];
    float p    = (float)c * (1.0f / (float)NQ);
    float ent  = p * logf(p + 1e-10f);
    float used = (c > 0) ? 1.0f : 0.0f;
    #pragma unroll
    for (int off = 32; off; off >>= 1) {
        ent  += __shfl_xor(ent, off);
        used += __shfl_xor(used, off);
    }
    __shared__ float se[16], su[16];
    int w = t >> 6, l = t & 63;
    if (l == 0) { se[w] = ent; su[w] = used; }
    __syncthreads();
    if (t == 0) {
        float E = 0.f, U = 0.f;
        #pragma unroll
        for (int i = 0; i < 16; ++i) { E += se[i]; U += su[i]; }
        float L = out3[0];                             // loss accumulated here
        out3[0] = L * 1.25f / 8388608.0f;              // vq_loss (q + 0.25*e)
        out3[1] = expf(-E);                            // perplexity
        out3[2] = U * (1.0f / 1024.0f);                // codebook_usage
    }
}

// ---------- launch (5 kernels, 0 memsets) ----------
// d_out (f32, 8519683): [0,8388608) quantized | [8388608,8519680) idx | 3 scalars
// flag_list aliases the quantized region (consumed by k_rescue before
// k_gather_loss overwrites it — stream-ordered).
// d_ws: counts[1024]@0 | wB u16[131072]@4096 | wInvD f64[1024]@266240
//       | wB2D f64[1024]@274432 | nflag@282624
extern "C" void kernel_launch(void* const* d_in, const int* in_sizes, int n_in,
                              void* d_out, int out_size, void* d_ws, size_t ws_size,
                              hipStream_t stream) {
    const float* inp = (const float*)d_in[0];   // [32,4096,64] f32
    const float* emb = (const float*)d_in[1];   // [1024,64] f32

    float* qout      = (float*)d_out;
    int*   flag_list = (int*)d_out;             // aliases qout (see note)
    float* idx_out   = (float*)d_out + 8388608;
    float* out3      = (float*)d_out + 8519680;

    int*            counts = (int*)d_ws;
    unsigned short* wB     = (unsigned short*)((char*)d_ws + 4096);
    double*         wInvD  = (double*)((char*)d_ws + 266240);
    double*         wB2D   = (double*)((char*)d_ws + 274432);
    int*            nflag  = (int*)((char*)d_ws + 282624);

    hipLaunchKernelGGL(k_prep,        dim3(4),     dim3(256),  0, stream,
                       emb, wB, wInvD, wB2D, counts, nflag, out3);
    hipLaunchKernelGGL(k_assign,      dim3(1024),  dim3(256),  0, stream,
                       inp, wB, idx_out, flag_list, nflag);
    hipLaunchKernelGGL(k_rescue,      dim3(RGRID), dim3(256),  0, stream,
                       inp, emb, wInvD, wB2D, flag_list, nflag, idx_out);
    hipLaunchKernelGGL(k_gather_loss, dim3(2048),  dim3(256),  0, stream,
                       inp, emb, idx_out, qout, out3);
    hipLaunchKernelGGL(k_stats,       dim3(1),     dim3(1024), 0, stream, idx_out, out3);
}